// Round 2
// 1426.425 us; speedup vs baseline: 1.2075x; 1.2075x over previous
//
#include <hip/hip_runtime.h>

#define T_ 512
#define N_ 60
#define F_ 2
#define C_ 64
#define H_ 512
#define IN_ 3840
#define FOURH 2048
#define PRED_SZ 61440
#define ADJ_SZ 1843200
#define LDSK 40   // padded LDS row stride in bf16 units (2-way conflicts only)

typedef __attribute__((ext_vector_type(8))) short bf8;
typedef __attribute__((ext_vector_type(4))) float f4;

__device__ __forceinline__ unsigned short f2bf(float f)
{
    unsigned int u = __float_as_uint(f);
    u = (u + 0x7FFFu + ((u >> 16) & 1u)) >> 16;
    return (unsigned short)u;
}

// cast fp32 -> bf16 (weights, once per launch)
__global__ void cast_k(const float* src, unsigned short* dst, int n)
{
    int i = blockIdx.x * 256 + threadIdx.x;
    if (i < n) dst[i] = f2bf(src[i]);
}

// h_bf = 0, c = 0, out frame 0 = feature_input[0]
__global__ void init_k(unsigned short* h_bf, float* c, const float* feat, float* out)
{
    int i = blockIdx.x * 256 + threadIdx.x;   // 1024 blocks -> 262144
    h_bf[i] = 0;
    c[i] = 0.0f;
    if (i < PRED_SZ) out[i] = feat[i];
}

// Encoder GCN. Multi-frame: blockIdx.x = frame*512 + t.
__global__ void gcn_enc_k(const float* x, const float* adj,
                          const float* W, const float* b, unsigned short* g_bf)
{
    __shared__ float sA[N_][N_];
    __shared__ float sh[N_][C_];
    __shared__ float snorm[N_];
    __shared__ float sW0[C_];
    __shared__ float sW1[C_];
    __shared__ float sb[C_];

    int frame = blockIdx.x >> 9;       // T_ == 512
    int t = blockIdx.x & 511;
    const float* xf = x + (long)frame * PRED_SZ;
    const float* af = adj + (long)frame * ADJ_SZ;
    unsigned short* gf = g_bf + (long)frame * ((long)T_ * IN_);
    int tid = threadIdx.x;

    if (tid < C_) {
        sW0[tid] = W[tid];
        sW1[tid] = W[C_ + tid];
        sb[tid] = b[tid];
    }
    for (int l = tid; l < N_ * N_; l += 256) {
        int i = l / N_;
        int j = l - i * N_;
        float a = af[(long)t * N_ * N_ + l];
        if (i == j) a += 1.0f;
        sA[i][j] = a;
    }
    __syncthreads();

    for (int l = tid; l < N_ * C_; l += 256) {
        int n = l >> 6;
        int cc = l & 63;
        float x0 = xf[((long)t * N_ + n) * F_ + 0];
        float x1 = xf[((long)t * N_ + n) * F_ + 1];
        sh[n][cc] = x0 * sW0[cc] + x1 * sW1[cc];
    }
    if (tid < N_) {
        float d = 0.0f;
        for (int j = 0; j < N_; ++j) d += sA[tid][j];
        snorm[tid] = (d > 0.0f) ? rsqrtf(d) : 0.0f;
    }
    __syncthreads();

    for (int l = tid; l < N_ * C_; l += 256) {
        int n = l >> 6;
        sh[n][l & 63] *= snorm[n];
    }
    __syncthreads();

    for (int l = tid; l < N_ * C_; l += 256) {
        int i = l >> 6;
        int cc = l & 63;
        float s = 0.0f;
        for (int j = 0; j < N_; ++j) s += sA[i][j] * sh[j][cc];
        gf[(long)t * IN_ + l] = f2bf(snorm[i] * s + sb[cc]);
    }
}

// Decoder GCN: radius-graph built in-kernel from pred (reads pred from out frame)
__global__ void gcn_dec_k(const float* pred, const float* stdv, const float* meanv,
                          const float* W, const float* b, unsigned short* g_bf)
{
    __shared__ float sA[N_][N_];
    __shared__ float sh[N_][C_];
    __shared__ float snorm[N_];
    __shared__ float sW0[C_];
    __shared__ float sW1[C_];
    __shared__ float sb[C_];
    __shared__ float sx0[N_];
    __shared__ float sx1[N_];
    __shared__ int sex[N_];

    int t = blockIdx.x;
    int tid = threadIdx.x;

    if (tid < C_) {
        sW0[tid] = W[tid];
        sW1[tid] = W[C_ + tid];
        sb[tid] = b[tid];
    }
    if (tid < N_) {
        float dx = pred[(long)t * 120 + tid * 2 + 0] * stdv[0] + meanv[0];
        float dy = pred[(long)t * 120 + tid * 2 + 1] * stdv[1] + meanv[1];
        sx0[tid] = dx;
        sx1[tid] = dy;
        sex[tid] = (dx > 0.04f) && (dy > 0.04f);
    }
    __syncthreads();

    for (int l = tid; l < N_ * N_; l += 256) {
        int i = l / N_;
        int j = l - i * N_;
        float dx = sx0[i] - sx0[j];
        float dy = sx1[i] - sx1[j];
        float d = sqrtf(dx * dx + dy * dy);
        int conn = ((d > 0.0f) && (d < 10.0f)) || (i == j);
        float a = (sex[i] && sex[j] && conn) ? 1.0f : 0.0f;
        if (i == j) a += 1.0f;     // GCN self-loop on top of radius graph
        sA[i][j] = a;
    }
    __syncthreads();

    for (int l = tid; l < N_ * C_; l += 256) {
        int n = l >> 6;
        int cc = l & 63;
        float x0 = pred[(long)t * 120 + n * 2 + 0];
        float x1 = pred[(long)t * 120 + n * 2 + 1];
        sh[n][cc] = x0 * sW0[cc] + x1 * sW1[cc];
    }
    if (tid < N_) {
        float d = 0.0f;
        for (int j = 0; j < N_; ++j) d += sA[tid][j];
        snorm[tid] = (d > 0.0f) ? rsqrtf(d) : 0.0f;
    }
    __syncthreads();

    for (int l = tid; l < N_ * C_; l += 256) {
        int n = l >> 6;
        sh[n][l & 63] *= snorm[n];
    }
    __syncthreads();

    for (int l = tid; l < N_ * C_; l += 256) {
        int i = l >> 6;
        int cc = l & 63;
        float s = 0.0f;
        for (int j = 0; j < N_; ++j) s += sA[i][j] * sh[j][cc];
        g_bf[(long)t * IN_ + l] = f2bf(snorm[i] * s + sb[cc]);
    }
}

// ---------------------------------------------------------------------------
// MFMA GEMM: C[M,Nc] = A(bf16)[M,K] @ B (+bias), fp32 accumulate.
// BT=1: B stored [Nc][K]; BT=0: B stored [K][Nc].
// BBF=1: B is bf16; BBF=0: B is fp32 (cast during staging).
// mode 0: Cf = acc + bias1 + bias2      (gates init)
// mode 1: Cf += acc                     (gates accumulate)
// mode 2: Cbf = bf16(relu(acc + bias1)) (MLP hidden)
// mode 3: Cf = acc + bias1              (pred)
// 64x64 tile, BK=32, 256 threads = 4 waves, each wave 32x32 via 2x2 mfma 16x16x32.
// ---------------------------------------------------------------------------
__global__ __launch_bounds__(256) void mgemm(
    const unsigned short* Abf, const void* Bp,
    const float* bias1, const float* bias2,
    float* Cf, unsigned short* Cbf,
    int M, int Nc, int K, int BT, int BBF, int mode)
{
    __shared__ unsigned short As[64 * LDSK];
    __shared__ unsigned short Bs[64 * LDSK];

    int tid = threadIdx.x;
    int wave = tid >> 6;
    int lane = tid & 63;
    int quad = lane >> 4;
    int l16 = lane & 15;
    int wr = (wave >> 1) * 32;
    int wc = (wave & 1) * 32;
    int row0 = blockIdx.y * 64;
    int col0 = blockIdx.x * 64;

    f4 acc00 = {0.f, 0.f, 0.f, 0.f};
    f4 acc01 = {0.f, 0.f, 0.f, 0.f};
    f4 acc10 = {0.f, 0.f, 0.f, 0.f};
    f4 acc11 = {0.f, 0.f, 0.f, 0.f};

    const ushort4 zu = make_ushort4(0, 0, 0, 0);

    for (int k0 = 0; k0 < K; k0 += 32) {
        // --- stage A tile: 64 rows x 32 k (bf16) ---
        {
            int r = tid >> 2;
            int ko = (tid & 3) * 8;
            int gm = row0 + r;
            int gk = k0 + ko;
            ushort4 v0 = zu, v1 = zu;
            if (gm < M) {
                if (gk + 4 <= K) v0 = *(const ushort4*)&Abf[(long)gm * K + gk];
                if (gk + 8 <= K) v1 = *(const ushort4*)&Abf[(long)gm * K + gk + 4];
            }
            *(ushort4*)&As[r * LDSK + ko]     = v0;
            *(ushort4*)&As[r * LDSK + ko + 4] = v1;
        }
        // --- stage B tile into Bs[n][k] ---
        if (BT) {
            int n = tid >> 2;
            int ko = (tid & 3) * 8;
            int gn = col0 + n;
            int gk = k0 + ko;
            ushort4 v0 = zu, v1 = zu;
            if (gn < Nc) {
                if (BBF) {
                    const unsigned short* Bb = (const unsigned short*)Bp;
                    if (gk + 4 <= K) v0 = *(const ushort4*)&Bb[(long)gn * K + gk];
                    if (gk + 8 <= K) v1 = *(const ushort4*)&Bb[(long)gn * K + gk + 4];
                } else {
                    const float* Bf = (const float*)Bp;
                    if (gk + 4 <= K) {
                        float4 f = *(const float4*)&Bf[(long)gn * K + gk];
                        v0 = make_ushort4(f2bf(f.x), f2bf(f.y), f2bf(f.z), f2bf(f.w));
                    }
                    if (gk + 8 <= K) {
                        float4 f = *(const float4*)&Bf[(long)gn * K + gk + 4];
                        v1 = make_ushort4(f2bf(f.x), f2bf(f.y), f2bf(f.z), f2bf(f.w));
                    }
                }
            }
            *(ushort4*)&Bs[n * LDSK + ko]     = v0;
            *(ushort4*)&Bs[n * LDSK + ko + 4] = v1;
        } else {
            int kk = tid >> 3;
            int np = (tid & 7) * 8;
            int gk = k0 + kk;
            int gn0 = col0 + np;
            unsigned short vals[8];
            for (int i = 0; i < 8; ++i) vals[i] = 0;
            if (gk < K) {
                if (BBF) {
                    const unsigned short* Bb = (const unsigned short*)Bp;
                    if (gn0 + 4 <= Nc) {
                        ushort4 u = *(const ushort4*)&Bb[(long)gk * Nc + gn0];
                        vals[0] = u.x; vals[1] = u.y; vals[2] = u.z; vals[3] = u.w;
                    }
                    if (gn0 + 8 <= Nc) {
                        ushort4 u = *(const ushort4*)&Bb[(long)gk * Nc + gn0 + 4];
                        vals[4] = u.x; vals[5] = u.y; vals[6] = u.z; vals[7] = u.w;
                    }
                } else {
                    const float* Bf = (const float*)Bp;
                    if (gn0 + 4 <= Nc) {
                        float4 f = *(const float4*)&Bf[(long)gk * Nc + gn0];
                        vals[0] = f2bf(f.x); vals[1] = f2bf(f.y); vals[2] = f2bf(f.z); vals[3] = f2bf(f.w);
                    }
                    if (gn0 + 8 <= Nc) {
                        float4 f = *(const float4*)&Bf[(long)gk * Nc + gn0 + 4];
                        vals[4] = f2bf(f.x); vals[5] = f2bf(f.y); vals[6] = f2bf(f.z); vals[7] = f2bf(f.w);
                    }
                }
            }
            for (int i = 0; i < 8; ++i) Bs[(np + i) * LDSK + kk] = vals[i];
        }
        __syncthreads();

        // --- fragments + 4 MFMAs ---
        bf8 a0 = *(const bf8*)&As[(wr + l16) * LDSK + quad * 8];
        bf8 a1 = *(const bf8*)&As[(wr + 16 + l16) * LDSK + quad * 8];
        bf8 b0 = *(const bf8*)&Bs[(wc + l16) * LDSK + quad * 8];
        bf8 b1 = *(const bf8*)&Bs[(wc + 16 + l16) * LDSK + quad * 8];

        acc00 = __builtin_amdgcn_mfma_f32_16x16x32_bf16(a0, b0, acc00, 0, 0, 0);
        acc01 = __builtin_amdgcn_mfma_f32_16x16x32_bf16(a0, b1, acc01, 0, 0, 0);
        acc10 = __builtin_amdgcn_mfma_f32_16x16x32_bf16(a1, b0, acc10, 0, 0, 0);
        acc11 = __builtin_amdgcn_mfma_f32_16x16x32_bf16(a1, b1, acc11, 0, 0, 0);
        __syncthreads();
    }

    // --- epilogue: D[row=quad*4+r][col=l16] per 16x16 tile ---
    for (int mi = 0; mi < 2; ++mi) {
        for (int ni = 0; ni < 2; ++ni) {
            for (int r = 0; r < 4; ++r) {
                int gm = row0 + wr + mi * 16 + quad * 4 + r;
                int gn = col0 + wc + ni * 16 + l16;
                if (gm >= M || gn >= Nc) continue;
                float v;
                if (mi == 0 && ni == 0) v = acc00[r];
                else if (mi == 0)       v = acc01[r];
                else if (ni == 0)       v = acc10[r];
                else                    v = acc11[r];
                long idx = (long)gm * Nc + gn;
                if (mode == 0) {
                    Cf[idx] = v + bias1[gn] + bias2[gn];
                } else if (mode == 1) {
                    Cf[idx] += v;
                } else if (mode == 2) {
                    v += bias1[gn];
                    if (v < 0.0f) v = 0.0f;
                    Cbf[idx] = f2bf(v);
                } else {
                    Cf[idx] = v + bias1[gn];
                }
            }
        }
    }
}

// gates [T,4H] order (i,f,g,o) -> h_bf (bf16), c (fp32)
__global__ void lstm_k(const float* gates, unsigned short* h_bf, float* c)
{
    int idx = blockIdx.x * 256 + threadIdx.x;   // 1024 blocks -> 262144
    int t = idx >> 9;
    int j = idx & 511;
    const float* gr = gates + (long)t * FOURH;
    float ig = 1.0f / (1.0f + expf(-gr[j]));
    float fg = 1.0f / (1.0f + expf(-gr[512 + j]));
    float gg = tanhf(gr[1024 + j]);
    float og = 1.0f / (1.0f + expf(-gr[1536 + j]));
    float cn = fg * c[idx] + ig * gg;
    c[idx] = cn;
    h_bf[idx] = f2bf(og * tanhf(cn));
}

extern "C" void kernel_launch(void* const* d_in, const int* in_sizes, int n_in,
                              void* d_out, int out_size, void* d_ws, size_t ws_size,
                              hipStream_t stream)
{
    const float* feat  = (const float*)d_in[0];
    const float* adjin = (const float*)d_in[1];
    const float* stdv  = (const float*)d_in[2];
    const float* meanv = (const float*)d_in[3];
    const float* gcnW  = (const float*)d_in[4];
    const float* gcnb  = (const float*)d_in[5];
    const float* Wih   = (const float*)d_in[6];
    const float* Whh   = (const float*)d_in[7];
    const float* bih   = (const float*)d_in[8];
    const float* bhh   = (const float*)d_in[9];
    const float* W1    = (const float*)d_in[10];
    const float* b1    = (const float*)d_in[11];
    const float* W2    = (const float*)d_in[12];
    const float* b2    = (const float*)d_in[13];
    const float* W3    = (const float*)d_in[14];
    const float* b3    = (const float*)d_in[15];
    const float* W4    = (const float*)d_in[16];
    const float* b4    = (const float*)d_in[17];
    float* out = (float*)d_out;

    // Batched-encoder layout needs 49,156,096 B of workspace.
    int batched = (ws_size >= (size_t)49300000u) ? 1 : 0;

    if (batched) {
        // --- layout (batched): 5-slot gates + 5-slot g ---
        float* gates = (float*)d_ws;                    // 5 * 1,048,576 f
        float* c     = gates + 5 * 1048576;             //     262,144 f
        unsigned short* g_bf   = (unsigned short*)(c + 262144);  // 5 * 1,966,080
        unsigned short* h_bf   = g_bf + 5 * 1966080;    //   262,144
        unsigned short* m1_bf  = h_bf + 262144;         //   262,144
        unsigned short* m2_bf  = m1_bf + 262144;        //   526,336
        unsigned short* m3_bf  = m2_bf + 526336;        //   262,144
        unsigned short* Whh_bf = m3_bf + 262144;        // 1,048,576
        unsigned short* W1_bf  = Whh_bf + 1048576;      //   262,144
        unsigned short* W2_bf  = W1_bf + 262144;        //   526,336
        unsigned short* W3_bf  = W2_bf + 526336;        //   526,336
        unsigned short* W4_bf  = W3_bf + 526336;        //    61,440

        cast_k<<<(1048576 + 255) / 256, 256, 0, stream>>>(Whh, Whh_bf, 1048576);
        cast_k<<<(262144 + 255) / 256, 256, 0, stream>>>(W1, W1_bf, 262144);
        cast_k<<<(526336 + 255) / 256, 256, 0, stream>>>(W2, W2_bf, 526336);
        cast_k<<<(526336 + 255) / 256, 256, 0, stream>>>(W3, W3_bf, 526336);
        cast_k<<<(61440 + 255) / 256, 256, 0, stream>>>(W4, W4_bf, 61440);
        init_k<<<1024, 256, 0, stream>>>(h_bf, c, feat, out);

        // --- batched encoder: 5 input frames through GCN + Wih GEMM in one go ---
        gcn_enc_k<<<5 * T_, 256, 0, stream>>>(feat, adjin, gcnW, gcnb, g_bf);
        // pre-gates[frame] = g[frame] @ Wih^T + bih + bhh ; M = 2560 -> 1280 blocks
        mgemm<<<dim3(32, 40), 256, 0, stream>>>(g_bf, Wih, bih, bhh, gates, (unsigned short*)0,
                                                5 * T_, FOURH, IN_, 1, 0, 0);

        for (int step = 0; step < 7; ++step) {
            float* gs;
            if (step < 5) {
                gs = gates + (long)step * 1048576;
            } else {
                gs = gates;   // slot 0 is free after step 0
                gcn_dec_k<<<T_, 256, 0, stream>>>(out + (long)step * PRED_SZ,
                                                  stdv, meanv, gcnW, gcnb, g_bf);
                mgemm<<<dim3(32, 8), 256, 0, stream>>>(g_bf, Wih, bih, bhh, gs, (unsigned short*)0,
                                                       T_, FOURH, IN_, 1, 0, 0);
            }
            // gates += h @ Whh^T (h = 0 at step 0 -> no-op add, preserves semantics)
            mgemm<<<dim3(32, 8), 256, 0, stream>>>(h_bf, Whh_bf, (const float*)0, (const float*)0,
                                                   gs, (unsigned short*)0, T_, FOURH, H_, 1, 1, 1);
            lstm_k<<<1024, 256, 0, stream>>>(gs, h_bf, c);

            // MLP: h -> 512 -> 1028 -> 512 -> 120 (writes pred directly into out)
            mgemm<<<dim3(8, 8), 256, 0, stream>>>(h_bf, W1_bf, b1, (const float*)0,
                                                  (float*)0, m1_bf, T_, 512, 512, 0, 1, 2);
            mgemm<<<dim3(17, 8), 256, 0, stream>>>(m1_bf, W2_bf, b2, (const float*)0,
                                                   (float*)0, m2_bf, T_, 1028, 512, 0, 1, 2);
            mgemm<<<dim3(8, 8), 256, 0, stream>>>(m2_bf, W3_bf, b3, (const float*)0,
                                                  (float*)0, m3_bf, T_, 512, 1028, 0, 1, 2);
            mgemm<<<dim3(2, 8), 256, 0, stream>>>(m3_bf, W4_bf, b4, (const float*)0,
                                                  out + (long)(step + 1) * PRED_SZ, (unsigned short*)0,
                                                  T_, 120, 512, 0, 1, 3);
        }
    } else {
        // --- fallback: sequential per-step path (previous behavior) ---
        float* gates = (float*)d_ws;                //   1,048,576 f
        float* c     = gates + 1048576;             //     262,144 f
        unsigned short* g_bf   = (unsigned short*)(c + 262144);  // 1,966,080
        unsigned short* h_bf   = g_bf + 1966080;    //   262,144
        unsigned short* m1_bf  = h_bf + 262144;     //   262,144
        unsigned short* m2_bf  = m1_bf + 262144;    //   526,336
        unsigned short* m3_bf  = m2_bf + 526336;    //   262,144
        unsigned short* Whh_bf = m3_bf + 262144;    // 1,048,576
        unsigned short* W1_bf  = Whh_bf + 1048576;  //   262,144
        unsigned short* W2_bf  = W1_bf + 262144;    //   526,336
        unsigned short* W3_bf  = W2_bf + 526336;    //   526,336
        unsigned short* W4_bf  = W3_bf + 526336;    //    61,440
        unsigned short* Wih_bf = W4_bf + 61440;     // 7,864,320 (only if ws allows)
        int pre_ih = (ws_size >= (size_t)34u * 1024u * 1024u) ? 1 : 0;

        cast_k<<<(1048576 + 255) / 256, 256, 0, stream>>>(Whh, Whh_bf, 1048576);
        cast_k<<<(262144 + 255) / 256, 256, 0, stream>>>(W1, W1_bf, 262144);
        cast_k<<<(526336 + 255) / 256, 256, 0, stream>>>(W2, W2_bf, 526336);
        cast_k<<<(526336 + 255) / 256, 256, 0, stream>>>(W3, W3_bf, 526336);
        cast_k<<<(61440 + 255) / 256, 256, 0, stream>>>(W4, W4_bf, 61440);
        if (pre_ih)
            cast_k<<<(7864320 + 255) / 256, 256, 0, stream>>>(Wih, Wih_bf, 7864320);

        init_k<<<1024, 256, 0, stream>>>(h_bf, c, feat, out);

        for (int step = 0; step < 7; ++step) {
            if (step < 5)
                gcn_enc_k<<<T_, 256, 0, stream>>>(feat + (long)step * PRED_SZ,
                                                  adjin + (long)step * ADJ_SZ,
                                                  gcnW, gcnb, g_bf);
            else
                gcn_dec_k<<<T_, 256, 0, stream>>>(out + (long)step * PRED_SZ,
                                                  stdv, meanv, gcnW, gcnb, g_bf);

            if (pre_ih)
                mgemm<<<dim3(32, 8), 256, 0, stream>>>(g_bf, Wih_bf, bih, bhh, gates, (unsigned short*)0,
                                                       T_, FOURH, IN_, 1, 1, 0);
            else
                mgemm<<<dim3(32, 8), 256, 0, stream>>>(g_bf, Wih, bih, bhh, gates, (unsigned short*)0,
                                                       T_, FOURH, IN_, 1, 0, 0);
            mgemm<<<dim3(32, 8), 256, 0, stream>>>(h_bf, Whh_bf, (const float*)0, (const float*)0,
                                                   gates, (unsigned short*)0, T_, FOURH, H_, 1, 1, 1);
            lstm_k<<<1024, 256, 0, stream>>>(gates, h_bf, c);

            mgemm<<<dim3(8, 8), 256, 0, stream>>>(h_bf, W1_bf, b1, (const float*)0,
                                                  (float*)0, m1_bf, T_, 512, 512, 0, 1, 2);
            mgemm<<<dim3(17, 8), 256, 0, stream>>>(m1_bf, W2_bf, b2, (const float*)0,
                                                   (float*)0, m2_bf, T_, 1028, 512, 0, 1, 2);
            mgemm<<<dim3(8, 8), 256, 0, stream>>>(m2_bf, W3_bf, b3, (const float*)0,
                                                  (float*)0, m3_bf, T_, 512, 1028, 0, 1, 2);
            mgemm<<<dim3(2, 8), 256, 0, stream>>>(m3_bf, W4_bf, b4, (const float*)0,
                                                  out + (long)(step + 1) * PRED_SZ, (unsigned short*)0,
                                                  T_, 120, 512, 0, 1, 3);
        }
    }
}

// Round 3
// 1401.393 us; speedup vs baseline: 1.2291x; 1.0179x over previous
//
#include <hip/hip_runtime.h>

#define T_ 512
#define N_ 60
#define F_ 2
#define C_ 64
#define H_ 512
#define IN_ 3840
#define FOURH 2048
#define PRED_SZ 61440
#define ADJ_SZ 1843200
#define LDSK 40   // padded LDS row stride in bf16 units (2-way conflicts only)

typedef __attribute__((ext_vector_type(8))) short bf8;
typedef __attribute__((ext_vector_type(4))) float f4;

__device__ __forceinline__ unsigned short f2bf(float f)
{
    unsigned int u = __float_as_uint(f);
    u = (u + 0x7FFFu + ((u >> 16) & 1u)) >> 16;
    return (unsigned short)u;
}

// cast fp32 -> bf16 (weights, once per launch)
__global__ void cast_k(const float* src, unsigned short* dst, int n)
{
    int i = blockIdx.x * 256 + threadIdx.x;
    if (i < n) dst[i] = f2bf(src[i]);
}

// h (both ping-pong buffers) = 0, c = 0, out frame 0 = feature_input[0]
__global__ void init_k(unsigned short* h_bf, float* c, const float* feat, float* out)
{
    int i = blockIdx.x * 256 + threadIdx.x;   // 1024 blocks -> 262144
    h_bf[i] = 0;
    h_bf[i + 262144] = 0;   // second ping-pong buffer (contiguous)
    c[i] = 0.0f;
    if (i < PRED_SZ) out[i] = feat[i];
}

// Encoder GCN. Multi-frame: blockIdx.x = frame*512 + t.
__global__ void gcn_enc_k(const float* x, const float* adj,
                          const float* W, const float* b, unsigned short* g_bf)
{
    __shared__ float sA[N_][N_];
    __shared__ float sh[N_][C_];
    __shared__ float snorm[N_];
    __shared__ float sW0[C_];
    __shared__ float sW1[C_];
    __shared__ float sb[C_];

    int frame = blockIdx.x >> 9;       // T_ == 512
    int t = blockIdx.x & 511;
    const float* xf = x + (long)frame * PRED_SZ;
    const float* af = adj + (long)frame * ADJ_SZ;
    unsigned short* gf = g_bf + (long)frame * ((long)T_ * IN_);
    int tid = threadIdx.x;

    if (tid < C_) {
        sW0[tid] = W[tid];
        sW1[tid] = W[C_ + tid];
        sb[tid] = b[tid];
    }
    for (int l = tid; l < N_ * N_; l += 256) {
        int i = l / N_;
        int j = l - i * N_;
        float a = af[(long)t * N_ * N_ + l];
        if (i == j) a += 1.0f;
        sA[i][j] = a;
    }
    __syncthreads();

    for (int l = tid; l < N_ * C_; l += 256) {
        int n = l >> 6;
        int cc = l & 63;
        float x0 = xf[((long)t * N_ + n) * F_ + 0];
        float x1 = xf[((long)t * N_ + n) * F_ + 1];
        sh[n][cc] = x0 * sW0[cc] + x1 * sW1[cc];
    }
    if (tid < N_) {
        float d = 0.0f;
        for (int j = 0; j < N_; ++j) d += sA[tid][j];
        snorm[tid] = (d > 0.0f) ? rsqrtf(d) : 0.0f;
    }
    __syncthreads();

    for (int l = tid; l < N_ * C_; l += 256) {
        int n = l >> 6;
        sh[n][l & 63] *= snorm[n];
    }
    __syncthreads();

    for (int l = tid; l < N_ * C_; l += 256) {
        int i = l >> 6;
        int cc = l & 63;
        float s = 0.0f;
        for (int j = 0; j < N_; ++j) s += sA[i][j] * sh[j][cc];
        gf[(long)t * IN_ + l] = f2bf(snorm[i] * s + sb[cc]);
    }
}

// Decoder GCN: radius-graph built in-kernel from pred (reads pred from out frame)
__global__ void gcn_dec_k(const float* pred, const float* stdv, const float* meanv,
                          const float* W, const float* b, unsigned short* g_bf)
{
    __shared__ float sA[N_][N_];
    __shared__ float sh[N_][C_];
    __shared__ float snorm[N_];
    __shared__ float sW0[C_];
    __shared__ float sW1[C_];
    __shared__ float sb[C_];
    __shared__ float sx0[N_];
    __shared__ float sx1[N_];
    __shared__ int sex[N_];

    int t = blockIdx.x;
    int tid = threadIdx.x;

    if (tid < C_) {
        sW0[tid] = W[tid];
        sW1[tid] = W[C_ + tid];
        sb[tid] = b[tid];
    }
    if (tid < N_) {
        float dx = pred[(long)t * 120 + tid * 2 + 0] * stdv[0] + meanv[0];
        float dy = pred[(long)t * 120 + tid * 2 + 1] * stdv[1] + meanv[1];
        sx0[tid] = dx;
        sx1[tid] = dy;
        sex[tid] = (dx > 0.04f) && (dy > 0.04f);
    }
    __syncthreads();

    for (int l = tid; l < N_ * N_; l += 256) {
        int i = l / N_;
        int j = l - i * N_;
        float dx = sx0[i] - sx0[j];
        float dy = sx1[i] - sx1[j];
        float d = sqrtf(dx * dx + dy * dy);
        int conn = ((d > 0.0f) && (d < 10.0f)) || (i == j);
        float a = (sex[i] && sex[j] && conn) ? 1.0f : 0.0f;
        if (i == j) a += 1.0f;     // GCN self-loop on top of radius graph
        sA[i][j] = a;
    }
    __syncthreads();

    for (int l = tid; l < N_ * C_; l += 256) {
        int n = l >> 6;
        int cc = l & 63;
        float x0 = pred[(long)t * 120 + n * 2 + 0];
        float x1 = pred[(long)t * 120 + n * 2 + 1];
        sh[n][cc] = x0 * sW0[cc] + x1 * sW1[cc];
    }
    if (tid < N_) {
        float d = 0.0f;
        for (int j = 0; j < N_; ++j) d += sA[tid][j];
        snorm[tid] = (d > 0.0f) ? rsqrtf(d) : 0.0f;
    }
    __syncthreads();

    for (int l = tid; l < N_ * C_; l += 256) {
        int n = l >> 6;
        sh[n][l & 63] *= snorm[n];
    }
    __syncthreads();

    for (int l = tid; l < N_ * C_; l += 256) {
        int i = l >> 6;
        int cc = l & 63;
        float s = 0.0f;
        for (int j = 0; j < N_; ++j) s += sA[i][j] * sh[j][cc];
        g_bf[(long)t * IN_ + l] = f2bf(snorm[i] * s + sb[cc]);
    }
}

// ---------------------------------------------------------------------------
// MFMA GEMM: C[M,Nc] = A(bf16)[M,K] @ B (+bias), fp32 accumulate.
// BT=1: B stored [Nc][K]; BT=0: B stored [K][Nc].
// BBF=1: B is bf16; BBF=0: B is fp32 (cast during staging).
// mode 0: Cf = acc + bias1 + bias2      (gates init)
// mode 1: Cf += acc                     (gates accumulate)
// mode 2: Cbf = bf16(relu(acc + bias1)) (MLP hidden)
// mode 3: Cf = acc + bias1              (pred)
// ---------------------------------------------------------------------------
__global__ __launch_bounds__(256) void mgemm(
    const unsigned short* Abf, const void* Bp,
    const float* bias1, const float* bias2,
    float* Cf, unsigned short* Cbf,
    int M, int Nc, int K, int BT, int BBF, int mode)
{
    __shared__ unsigned short As[64 * LDSK];
    __shared__ unsigned short Bs[64 * LDSK];

    int tid = threadIdx.x;
    int wave = tid >> 6;
    int lane = tid & 63;
    int quad = lane >> 4;
    int l16 = lane & 15;
    int wr = (wave >> 1) * 32;
    int wc = (wave & 1) * 32;
    int row0 = blockIdx.y * 64;
    int col0 = blockIdx.x * 64;

    f4 acc00 = {0.f, 0.f, 0.f, 0.f};
    f4 acc01 = {0.f, 0.f, 0.f, 0.f};
    f4 acc10 = {0.f, 0.f, 0.f, 0.f};
    f4 acc11 = {0.f, 0.f, 0.f, 0.f};

    const ushort4 zu = make_ushort4(0, 0, 0, 0);

    for (int k0 = 0; k0 < K; k0 += 32) {
        // --- stage A tile: 64 rows x 32 k (bf16) ---
        {
            int r = tid >> 2;
            int ko = (tid & 3) * 8;
            int gm = row0 + r;
            int gk = k0 + ko;
            ushort4 v0 = zu, v1 = zu;
            if (gm < M) {
                if (gk + 4 <= K) v0 = *(const ushort4*)&Abf[(long)gm * K + gk];
                if (gk + 8 <= K) v1 = *(const ushort4*)&Abf[(long)gm * K + gk + 4];
            }
            *(ushort4*)&As[r * LDSK + ko]     = v0;
            *(ushort4*)&As[r * LDSK + ko + 4] = v1;
        }
        // --- stage B tile into Bs[n][k] ---
        if (BT) {
            int n = tid >> 2;
            int ko = (tid & 3) * 8;
            int gn = col0 + n;
            int gk = k0 + ko;
            ushort4 v0 = zu, v1 = zu;
            if (gn < Nc) {
                if (BBF) {
                    const unsigned short* Bb = (const unsigned short*)Bp;
                    if (gk + 4 <= K) v0 = *(const ushort4*)&Bb[(long)gn * K + gk];
                    if (gk + 8 <= K) v1 = *(const ushort4*)&Bb[(long)gn * K + gk + 4];
                } else {
                    const float* Bf = (const float*)Bp;
                    if (gk + 4 <= K) {
                        float4 f = *(const float4*)&Bf[(long)gn * K + gk];
                        v0 = make_ushort4(f2bf(f.x), f2bf(f.y), f2bf(f.z), f2bf(f.w));
                    }
                    if (gk + 8 <= K) {
                        float4 f = *(const float4*)&Bf[(long)gn * K + gk + 4];
                        v1 = make_ushort4(f2bf(f.x), f2bf(f.y), f2bf(f.z), f2bf(f.w));
                    }
                }
            }
            *(ushort4*)&Bs[n * LDSK + ko]     = v0;
            *(ushort4*)&Bs[n * LDSK + ko + 4] = v1;
        } else {
            int kk = tid >> 3;
            int np = (tid & 7) * 8;
            int gk = k0 + kk;
            int gn0 = col0 + np;
            unsigned short vals[8];
            for (int i = 0; i < 8; ++i) vals[i] = 0;
            if (gk < K) {
                if (BBF) {
                    const unsigned short* Bb = (const unsigned short*)Bp;
                    if (gn0 + 4 <= Nc) {
                        ushort4 u = *(const ushort4*)&Bb[(long)gk * Nc + gn0];
                        vals[0] = u.x; vals[1] = u.y; vals[2] = u.z; vals[3] = u.w;
                    }
                    if (gn0 + 8 <= Nc) {
                        ushort4 u = *(const ushort4*)&Bb[(long)gk * Nc + gn0 + 4];
                        vals[4] = u.x; vals[5] = u.y; vals[6] = u.z; vals[7] = u.w;
                    }
                } else {
                    const float* Bf = (const float*)Bp;
                    if (gn0 + 4 <= Nc) {
                        float4 f = *(const float4*)&Bf[(long)gk * Nc + gn0];
                        vals[0] = f2bf(f.x); vals[1] = f2bf(f.y); vals[2] = f2bf(f.z); vals[3] = f2bf(f.w);
                    }
                    if (gn0 + 8 <= Nc) {
                        float4 f = *(const float4*)&Bf[(long)gk * Nc + gn0 + 4];
                        vals[4] = f2bf(f.x); vals[5] = f2bf(f.y); vals[6] = f2bf(f.z); vals[7] = f2bf(f.w);
                    }
                }
            }
            for (int i = 0; i < 8; ++i) Bs[(np + i) * LDSK + kk] = vals[i];
        }
        __syncthreads();

        // --- fragments + 4 MFMAs ---
        bf8 a0 = *(const bf8*)&As[(wr + l16) * LDSK + quad * 8];
        bf8 a1 = *(const bf8*)&As[(wr + 16 + l16) * LDSK + quad * 8];
        bf8 b0 = *(const bf8*)&Bs[(wc + l16) * LDSK + quad * 8];
        bf8 b1 = *(const bf8*)&Bs[(wc + 16 + l16) * LDSK + quad * 8];

        acc00 = __builtin_amdgcn_mfma_f32_16x16x32_bf16(a0, b0, acc00, 0, 0, 0);
        acc01 = __builtin_amdgcn_mfma_f32_16x16x32_bf16(a0, b1, acc01, 0, 0, 0);
        acc10 = __builtin_amdgcn_mfma_f32_16x16x32_bf16(a1, b0, acc10, 0, 0, 0);
        acc11 = __builtin_amdgcn_mfma_f32_16x16x32_bf16(a1, b1, acc11, 0, 0, 0);
        __syncthreads();
    }

    // --- epilogue: D[row=quad*4+r][col=l16] per 16x16 tile ---
    for (int mi = 0; mi < 2; ++mi) {
        for (int ni = 0; ni < 2; ++ni) {
            for (int r = 0; r < 4; ++r) {
                int gm = row0 + wr + mi * 16 + quad * 4 + r;
                int gn = col0 + wc + ni * 16 + l16;
                if (gm >= M || gn >= Nc) continue;
                float v;
                if (mi == 0 && ni == 0) v = acc00[r];
                else if (mi == 0)       v = acc01[r];
                else if (ni == 0)       v = acc10[r];
                else                    v = acc11[r];
                long idx = (long)gm * Nc + gn;
                if (mode == 0) {
                    Cf[idx] = v + bias1[gn] + bias2[gn];
                } else if (mode == 1) {
                    Cf[idx] += v;
                } else if (mode == 2) {
                    v += bias1[gn];
                    if (v < 0.0f) v = 0.0f;
                    Cbf[idx] = f2bf(v);
                } else {
                    Cf[idx] = v + bias1[gn];
                }
            }
        }
    }
}

// ---------------------------------------------------------------------------
// Fused h@Whh^T + LSTM pointwise.
// grid (8 j-blocks, 8 t-blocks), 256 threads. Block tile: 64 t-rows x 64 j.
// Wave w covers j-sub [j0 + w*16, +16) for ALL FOUR gates, so each thread
// holds i,f,g,o for its (t,j) in registers -> LSTM in epilogue, no exchange.
// pregates = g@Wih^T + bih + bhh (fp32, already computed).
// c updated in place (exclusive ownership per thread); h written to hnew.
// ---------------------------------------------------------------------------
__global__ __launch_bounds__(256) void whh_lstm_k(
    const unsigned short* hprev, const unsigned short* Whh_bf,
    const float* pregates, float* c, unsigned short* hnew)
{
    __shared__ unsigned short As[64 * LDSK];    // h rows: 64 x 32
    __shared__ unsigned short Bs[256 * LDSK];   // 4 gates x 64 j-rows x 32 k

    int tid = threadIdx.x;
    int wave = tid >> 6;
    int lane = tid & 63;
    int quad = lane >> 4;
    int l16 = lane & 15;
    int j0 = blockIdx.x * 64;
    int row0 = blockIdx.y * 64;

    f4 acc[4][4];   // [gate][m]
    for (int g = 0; g < 4; ++g)
        for (int m = 0; m < 4; ++m)
            acc[g][m] = f4{0.f, 0.f, 0.f, 0.f};

    for (int k0 = 0; k0 < H_; k0 += 32) {
        // stage A: 64 rows x 32 k (one uint4 = 8 bf16 per thread)
        {
            int r = tid >> 2;
            int ko = (tid & 3) * 8;
            uint4 v = *(const uint4*)&hprev[(long)(row0 + r) * H_ + k0 + ko];
            *(uint4*)&As[r * LDSK + ko] = v;
        }
        // stage B: 256 rows (gate = tid>>6, jj = tid&63), 32 k per row
        {
            int g = tid >> 6;
            int jj = tid & 63;
            long grow = (long)(g * H_ + j0 + jj) * H_ + k0;
            #pragma unroll
            for (int i = 0; i < 4; ++i) {
                uint4 v = *(const uint4*)&Whh_bf[grow + i * 8];
                *(uint4*)&Bs[tid * LDSK + i * 8] = v;
            }
        }
        __syncthreads();

        bf8 a[4], b[4];
        #pragma unroll
        for (int m = 0; m < 4; ++m)
            a[m] = *(const bf8*)&As[(m * 16 + l16) * LDSK + quad * 8];
        #pragma unroll
        for (int g = 0; g < 4; ++g)
            b[g] = *(const bf8*)&Bs[(g * 64 + wave * 16 + l16) * LDSK + quad * 8];

        #pragma unroll
        for (int g = 0; g < 4; ++g)
            #pragma unroll
            for (int m = 0; m < 4; ++m)
                acc[g][m] = __builtin_amdgcn_mfma_f32_16x16x32_bf16(a[m], b[g], acc[g][m], 0, 0, 0);
        __syncthreads();
    }

    // epilogue: LSTM pointwise; D row = m*16 + quad*4 + r, col = l16
    int j = j0 + wave * 16 + l16;
    #pragma unroll
    for (int m = 0; m < 4; ++m) {
        #pragma unroll
        for (int r = 0; r < 4; ++r) {
            int t = row0 + m * 16 + quad * 4 + r;
            const float* pg = pregates + (long)t * FOURH;
            float gi = pg[j]        + acc[0][m][r];
            float gf = pg[512 + j]  + acc[1][m][r];
            float gg = pg[1024 + j] + acc[2][m][r];
            float go = pg[1536 + j] + acc[3][m][r];
            float ig = 1.0f / (1.0f + expf(-gi));
            float fg = 1.0f / (1.0f + expf(-gf));
            float g2 = tanhf(gg);
            float og = 1.0f / (1.0f + expf(-go));
            long ci = (long)t * H_ + j;
            float cn = fg * c[ci] + ig * g2;
            c[ci] = cn;
            hnew[ci] = f2bf(og * tanhf(cn));
        }
    }
}

// gates [T,4H] order (i,f,g,o) -> h_bf (bf16), c (fp32)  [fallback path]
__global__ void lstm_k(const float* gates, unsigned short* h_bf, float* c)
{
    int idx = blockIdx.x * 256 + threadIdx.x;   // 1024 blocks -> 262144
    int t = idx >> 9;
    int j = idx & 511;
    const float* gr = gates + (long)t * FOURH;
    float ig = 1.0f / (1.0f + expf(-gr[j]));
    float fg = 1.0f / (1.0f + expf(-gr[512 + j]));
    float gg = tanhf(gr[1024 + j]);
    float og = 1.0f / (1.0f + expf(-gr[1536 + j]));
    float cn = fg * c[idx] + ig * gg;
    c[idx] = cn;
    h_bf[idx] = f2bf(og * tanhf(cn));
}

extern "C" void kernel_launch(void* const* d_in, const int* in_sizes, int n_in,
                              void* d_out, int out_size, void* d_ws, size_t ws_size,
                              hipStream_t stream)
{
    const float* feat  = (const float*)d_in[0];
    const float* adjin = (const float*)d_in[1];
    const float* stdv  = (const float*)d_in[2];
    const float* meanv = (const float*)d_in[3];
    const float* gcnW  = (const float*)d_in[4];
    const float* gcnb  = (const float*)d_in[5];
    const float* Wih   = (const float*)d_in[6];
    const float* Whh   = (const float*)d_in[7];
    const float* bih   = (const float*)d_in[8];
    const float* bhh   = (const float*)d_in[9];
    const float* W1    = (const float*)d_in[10];
    const float* b1    = (const float*)d_in[11];
    const float* W2    = (const float*)d_in[12];
    const float* b2    = (const float*)d_in[13];
    const float* W3    = (const float*)d_in[14];
    const float* b3    = (const float*)d_in[15];
    const float* W4    = (const float*)d_in[16];
    const float* b4    = (const float*)d_in[17];
    float* out = (float*)d_out;

    // Batched layout: 49,680,384 B; +Wih bf16 precast: 65,409,024 B.
    int batched = (ws_size >= (size_t)49680384u) ? 1 : 0;
    int pre_ih_b = (ws_size >= (size_t)65409024u) ? 1 : 0;

    if (batched) {
        float* gates = (float*)d_ws;                    // 5 * 1,048,576 f
        float* c     = gates + 5 * 1048576;             //     262,144 f
        unsigned short* g_bf   = (unsigned short*)(c + 262144);  // 5 * 1,966,080
        unsigned short* h_bf   = g_bf + 5 * 1966080;    //   262,144 (ping)
        unsigned short* h2_bf  = h_bf + 262144;         //   262,144 (pong)
        unsigned short* m1_bf  = h2_bf + 262144;        //   262,144
        unsigned short* m2_bf  = m1_bf + 262144;        //   526,336
        unsigned short* m3_bf  = m2_bf + 526336;        //   262,144
        unsigned short* Whh_bf = m3_bf + 262144;        // 1,048,576
        unsigned short* W1_bf  = Whh_bf + 1048576;      //   262,144
        unsigned short* W2_bf  = W1_bf + 262144;        //   526,336
        unsigned short* W3_bf  = W2_bf + 526336;        //   526,336
        unsigned short* W4_bf  = W3_bf + 526336;        //    61,440
        unsigned short* Wih_bf = W4_bf + 61440;         // 7,864,320 (if pre_ih_b)

        cast_k<<<(1048576 + 255) / 256, 256, 0, stream>>>(Whh, Whh_bf, 1048576);
        cast_k<<<(262144 + 255) / 256, 256, 0, stream>>>(W1, W1_bf, 262144);
        cast_k<<<(526336 + 255) / 256, 256, 0, stream>>>(W2, W2_bf, 526336);
        cast_k<<<(526336 + 255) / 256, 256, 0, stream>>>(W3, W3_bf, 526336);
        cast_k<<<(61440 + 255) / 256, 256, 0, stream>>>(W4, W4_bf, 61440);
        if (pre_ih_b)
            cast_k<<<(7864320 + 255) / 256, 256, 0, stream>>>(Wih, Wih_bf, 7864320);
        init_k<<<1024, 256, 0, stream>>>(h_bf, c, feat, out);

        // batched encoder: 5 input frames through GCN + Wih GEMM in one go
        gcn_enc_k<<<5 * T_, 256, 0, stream>>>(feat, adjin, gcnW, gcnb, g_bf);
        if (pre_ih_b)
            mgemm<<<dim3(32, 40), 256, 0, stream>>>(g_bf, Wih_bf, bih, bhh, gates, (unsigned short*)0,
                                                    5 * T_, FOURH, IN_, 1, 1, 0);
        else
            mgemm<<<dim3(32, 40), 256, 0, stream>>>(g_bf, Wih, bih, bhh, gates, (unsigned short*)0,
                                                    5 * T_, FOURH, IN_, 1, 0, 0);

        for (int step = 0; step < 7; ++step) {
            float* gs;
            if (step < 5) {
                gs = gates + (long)step * 1048576;
            } else {
                gs = gates;   // slot 0 free after step 0
                gcn_dec_k<<<T_, 256, 0, stream>>>(out + (long)step * PRED_SZ,
                                                  stdv, meanv, gcnW, gcnb, g_bf);
                if (pre_ih_b)
                    mgemm<<<dim3(32, 8), 256, 0, stream>>>(g_bf, Wih_bf, bih, bhh, gs, (unsigned short*)0,
                                                           T_, FOURH, IN_, 1, 1, 0);
                else
                    mgemm<<<dim3(32, 8), 256, 0, stream>>>(g_bf, Wih, bih, bhh, gs, (unsigned short*)0,
                                                           T_, FOURH, IN_, 1, 0, 0);
            }
            unsigned short* hp = (step & 1) ? h2_bf : h_bf;
            unsigned short* hn = (step & 1) ? h_bf : h2_bf;
            whh_lstm_k<<<dim3(8, 8), 256, 0, stream>>>(hp, Whh_bf, gs, c, hn);

            // MLP: h -> 512 -> 1028 -> 512 -> 120 (pred written into out)
            mgemm<<<dim3(8, 8), 256, 0, stream>>>(hn, W1_bf, b1, (const float*)0,
                                                  (float*)0, m1_bf, T_, 512, 512, 0, 1, 2);
            mgemm<<<dim3(17, 8), 256, 0, stream>>>(m1_bf, W2_bf, b2, (const float*)0,
                                                   (float*)0, m2_bf, T_, 1028, 512, 0, 1, 2);
            mgemm<<<dim3(8, 8), 256, 0, stream>>>(m2_bf, W3_bf, b3, (const float*)0,
                                                  (float*)0, m3_bf, T_, 512, 1028, 0, 1, 2);
            mgemm<<<dim3(2, 8), 256, 0, stream>>>(m3_bf, W4_bf, b4, (const float*)0,
                                                  out + (long)(step + 1) * PRED_SZ, (unsigned short*)0,
                                                  T_, 120, 512, 0, 1, 3);
        }
    } else {
        // --- fallback: sequential per-step path ---
        float* gates = (float*)d_ws;                //   1,048,576 f
        float* c     = gates + 1048576;             //     262,144 f
        unsigned short* g_bf   = (unsigned short*)(c + 262144);  // 1,966,080
        unsigned short* h_bf   = g_bf + 1966080;    //   262,144 (+ pong 262,144)
        unsigned short* h2_bf  = h_bf + 262144;
        unsigned short* m1_bf  = h2_bf + 262144;    //   262,144
        unsigned short* m2_bf  = m1_bf + 262144;    //   526,336
        unsigned short* m3_bf  = m2_bf + 526336;    //   262,144
        unsigned short* Whh_bf = m3_bf + 262144;    // 1,048,576
        unsigned short* W1_bf  = Whh_bf + 1048576;  //   262,144
        unsigned short* W2_bf  = W1_bf + 262144;    //   526,336
        unsigned short* W3_bf  = W2_bf + 526336;    //   526,336
        unsigned short* W4_bf  = W3_bf + 526336;    //    61,440
        unsigned short* Wih_bf = W4_bf + 61440;     // 7,864,320 (only if ws allows)
        int pre_ih = (ws_size >= (size_t)35u * 1024u * 1024u) ? 1 : 0;

        cast_k<<<(1048576 + 255) / 256, 256, 0, stream>>>(Whh, Whh_bf, 1048576);
        cast_k<<<(262144 + 255) / 256, 256, 0, stream>>>(W1, W1_bf, 262144);
        cast_k<<<(526336 + 255) / 256, 256, 0, stream>>>(W2, W2_bf, 526336);
        cast_k<<<(526336 + 255) / 256, 256, 0, stream>>>(W3, W3_bf, 526336);
        cast_k<<<(61440 + 255) / 256, 256, 0, stream>>>(W4, W4_bf, 61440);
        if (pre_ih)
            cast_k<<<(7864320 + 255) / 256, 256, 0, stream>>>(Wih, Wih_bf, 7864320);

        init_k<<<1024, 256, 0, stream>>>(h_bf, c, feat, out);

        for (int step = 0; step < 7; ++step) {
            if (step < 5)
                gcn_enc_k<<<T_, 256, 0, stream>>>(feat + (long)step * PRED_SZ,
                                                  adjin + (long)step * ADJ_SZ,
                                                  gcnW, gcnb, g_bf);
            else
                gcn_dec_k<<<T_, 256, 0, stream>>>(out + (long)step * PRED_SZ,
                                                  stdv, meanv, gcnW, gcnb, g_bf);

            if (pre_ih)
                mgemm<<<dim3(32, 8), 256, 0, stream>>>(g_bf, Wih_bf, bih, bhh, gates, (unsigned short*)0,
                                                       T_, FOURH, IN_, 1, 1, 0);
            else
                mgemm<<<dim3(32, 8), 256, 0, stream>>>(g_bf, Wih, bih, bhh, gates, (unsigned short*)0,
                                                       T_, FOURH, IN_, 1, 0, 0);
            mgemm<<<dim3(32, 8), 256, 0, stream>>>(h_bf, Whh_bf, (const float*)0, (const float*)0,
                                                   gates, (unsigned short*)0, T_, FOURH, H_, 1, 1, 1);
            lstm_k<<<1024, 256, 0, stream>>>(gates, h_bf, c);

            mgemm<<<dim3(8, 8), 256, 0, stream>>>(h_bf, W1_bf, b1, (const float*)0,
                                                  (float*)0, m1_bf, T_, 512, 512, 0, 1, 2);
            mgemm<<<dim3(17, 8), 256, 0, stream>>>(m1_bf, W2_bf, b2, (const float*)0,
                                                   (float*)0, m2_bf, T_, 1028, 512, 0, 1, 2);
            mgemm<<<dim3(8, 8), 256, 0, stream>>>(m2_bf, W3_bf, b3, (const float*)0,
                                                  (float*)0, m3_bf, T_, 512, 1028, 0, 1, 2);
            mgemm<<<dim3(2, 8), 256, 0, stream>>>(m3_bf, W4_bf, b4, (const float*)0,
                                                  out + (long)(step + 1) * PRED_SZ, (unsigned short*)0,
                                                  T_, 120, 512, 0, 1, 3);
        }
    }
}

// Round 4
// 1151.419 us; speedup vs baseline: 1.4959x; 1.2171x over previous
//
#include <hip/hip_runtime.h>

#define T_ 512
#define N_ 60
#define F_ 2
#define C_ 64
#define H_ 512
#define IN_ 3840
#define FOURH 2048
#define PRED_SZ 61440
#define ADJ_SZ 1843200
#define K2_ 128    // padded reduced-K for the Wih2 GEMM (120 real + 8 zero)
#define LDSK 40    // padded LDS row stride in bf16 units (2-way conflicts only)

typedef __attribute__((ext_vector_type(8))) short bf8;
typedef __attribute__((ext_vector_type(4))) float f4;

__device__ __forceinline__ unsigned short f2bf(float f)
{
    unsigned int u = __float_as_uint(f);
    u = (u + 0x7FFFu + ((u >> 16) & 1u)) >> 16;
    return (unsigned short)u;
}

// cast fp32 -> bf16 (weights, once per launch)
__global__ void cast_k(const float* src, unsigned short* dst, int n)
{
    int i = blockIdx.x * 256 + threadIdx.x;
    if (i < n) dst[i] = f2bf(src[i]);
}

// h (both ping-pong buffers) = 0, c = 0, out frame 0 = feature_input[0]
__global__ void init_k(unsigned short* h_bf, float* c, const float* feat, float* out)
{
    int i = blockIdx.x * 256 + threadIdx.x;   // 1024 blocks -> 262144
    h_bf[i] = 0;
    h_bf[i + 262144] = 0;   // second ping-pong buffer (contiguous)
    c[i] = 0.0f;
    if (i < PRED_SZ) out[i] = feat[i];
}

// ---------------------------------------------------------------------------
// Wih2[o, n*2+f] = sum_c Wih[o, n*64+c] * W[f,c]   (2048 x 120, pad to 128)
// biasAll[o] = bih[o] + bhh[o] + sum_k Wih[o,k]*b[k&63]
// One block per o-row; Wih row staged in LDS (coalesced read, 15 KB).
// ---------------------------------------------------------------------------
__global__ __launch_bounds__(256) void wih2_k(
    const float* Wih, const float* W, const float* b,
    const float* bih, const float* bhh,
    unsigned short* Wih2_bf, float* biasAll)
{
    __shared__ float row[IN_];     // 3840 floats
    __shared__ float wc[2][64];
    __shared__ float bb[64];
    __shared__ float red[256];

    int o = blockIdx.x;
    int tid = threadIdx.x;

    if (tid < 128) wc[tid >> 6][tid & 63] = W[tid];   // W is [2][64] row-major
    if (tid < 64) bb[tid] = b[tid];
    for (int k = tid; k < IN_; k += 256) row[k] = Wih[(long)o * IN_ + k];
    __syncthreads();

    if (tid < 128) {
        float s = 0.0f;
        if (tid < 120) {
            int n = tid >> 1;
            int f = tid & 1;
            for (int c = 0; c < 64; ++c) s += row[n * 64 + c] * wc[f][c];
        }
        Wih2_bf[(long)o * K2_ + tid] = f2bf(s);   // pad cols 120..127 = 0
    }

    float sb = 0.0f;
    for (int k = tid; k < IN_; k += 256) sb += row[k] * bb[k & 63];
    red[tid] = sb;
    __syncthreads();
    for (int s = 128; s > 0; s >>= 1) {
        if (tid < s) red[tid] += red[tid + s];
        __syncthreads();
    }
    if (tid == 0) biasAll[o] = bih[o] + bhh[o] + red[0];
}

// ---------------------------------------------------------------------------
// Encoder GCN (reduced): Y[t, n*2+f] = norm_n * sum_j A_nj * norm_j * x[j,f]
// blockIdx.x = frame*512 + t ; 128 threads. Output bf16 [row][128], pad = 0.
// ---------------------------------------------------------------------------
__global__ __launch_bounds__(128) void gcn_enc_y(
    const float* x, const float* adj, unsigned short* Y)
{
    __shared__ float sA[N_][N_];
    __shared__ float sx[N_][2];
    __shared__ float snorm[N_];

    int frame = blockIdx.x >> 9;
    int t = blockIdx.x & 511;
    const float* xf = x + (long)frame * PRED_SZ + (long)t * 120;
    const float* af = adj + (long)frame * ADJ_SZ + (long)t * 3600;
    int tid = threadIdx.x;

    for (int l = tid; l < N_ * N_; l += 128) {
        int i = l / N_;
        int j = l - i * N_;
        float a = af[l];
        if (i == j) a += 1.0f;
        sA[i][j] = a;
    }
    if (tid < 120) sx[tid >> 1][tid & 1] = xf[tid];
    __syncthreads();

    if (tid < N_) {
        float d = 0.0f;
        for (int j = 0; j < N_; ++j) d += sA[tid][j];
        snorm[tid] = (d > 0.0f) ? rsqrtf(d) : 0.0f;
    }
    __syncthreads();

    if (tid < 128) {
        float y = 0.0f;
        if (tid < 120) {
            int n = tid >> 1;
            int f = tid & 1;
            float s = 0.0f;
            for (int j = 0; j < N_; ++j) s += sA[n][j] * snorm[j] * sx[j][f];
            y = snorm[n] * s;
        }
        Y[(long)blockIdx.x * K2_ + tid] = f2bf(y);
    }
}

// ---------------------------------------------------------------------------
// Decoder GCN (reduced): radius graph from pred, then Y as above.
// grid 512, 128 threads.
// ---------------------------------------------------------------------------
__global__ __launch_bounds__(128) void gcn_dec_y(
    const float* pred, const float* stdv, const float* meanv, unsigned short* Y)
{
    __shared__ float sA[N_][N_];
    __shared__ float sx[N_][2];   // raw pred (GCN features)
    __shared__ float dx0[N_];
    __shared__ float dx1[N_];
    __shared__ int sex[N_];
    __shared__ float snorm[N_];

    int t = blockIdx.x;
    int tid = threadIdx.x;
    const float* pr = pred + (long)t * 120;

    if (tid < 120) sx[tid >> 1][tid & 1] = pr[tid];
    if (tid < N_) {
        float vx = pr[tid * 2 + 0] * stdv[0] + meanv[0];
        float vy = pr[tid * 2 + 1] * stdv[1] + meanv[1];
        dx0[tid] = vx;
        dx1[tid] = vy;
        sex[tid] = (vx > 0.04f) && (vy > 0.04f);
    }
    __syncthreads();

    for (int l = tid; l < N_ * N_; l += 128) {
        int i = l / N_;
        int j = l - i * N_;
        float ddx = dx0[i] - dx0[j];
        float ddy = dx1[i] - dx1[j];
        float d = sqrtf(ddx * ddx + ddy * ddy);
        int conn = ((d > 0.0f) && (d < 10.0f)) || (i == j);
        float a = (sex[i] && sex[j] && conn) ? 1.0f : 0.0f;
        if (i == j) a += 1.0f;     // GCN self-loop on top of radius graph
        sA[i][j] = a;
    }
    __syncthreads();

    if (tid < N_) {
        float d = 0.0f;
        for (int j = 0; j < N_; ++j) d += sA[tid][j];
        snorm[tid] = (d > 0.0f) ? rsqrtf(d) : 0.0f;
    }
    __syncthreads();

    if (tid < 128) {
        float y = 0.0f;
        if (tid < 120) {
            int n = tid >> 1;
            int f = tid & 1;
            float s = 0.0f;
            for (int j = 0; j < N_; ++j) s += sA[n][j] * snorm[j] * sx[j][f];
            y = snorm[n] * s;
        }
        Y[(long)t * K2_ + tid] = f2bf(y);
    }
}

// ---------------------------------------------------------------------------
// MFMA GEMM (bf16 B only): C[M,Nc] = A[M,K] @ B (+bias), fp32 accumulate.
// BT=1: B stored [Nc][K]; BT=0: B stored [K][Nc].
// mode 2: Cbf = bf16(relu(acc + bias1)) (MLP hidden)
// mode 3: Cf = acc + bias1              (gates / pred)
// Register-prefetch double buffering: next tile's global loads issue before
// the current tile's LDS write + MFMA, hiding HBM latency under compute.
// ---------------------------------------------------------------------------
template<int BT>
__global__ __launch_bounds__(256) void mgemm_t(
    const unsigned short* Abf, const unsigned short* Bb,
    const float* bias1, float* Cf, unsigned short* Cbf,
    int M, int Nc, int K, int mode)
{
    __shared__ unsigned short As[64 * LDSK];
    __shared__ unsigned short Bs[64 * LDSK];

    int tid = threadIdx.x;
    int wave = tid >> 6;
    int lane = tid & 63;
    int quad = lane >> 4;
    int l16 = lane & 15;
    int wr = (wave >> 1) * 32;
    int wc = (wave & 1) * 32;
    int row0 = blockIdx.y * 64;
    int col0 = blockIdx.x * 64;

    f4 acc00 = {0.f, 0.f, 0.f, 0.f};
    f4 acc01 = {0.f, 0.f, 0.f, 0.f};
    f4 acc10 = {0.f, 0.f, 0.f, 0.f};
    f4 acc11 = {0.f, 0.f, 0.f, 0.f};

    const ushort4 zu = make_ushort4(0, 0, 0, 0);

    int ar = tid >> 2;
    int ako = (tid & 3) * 8;
    int bkk = tid >> 3;            // BT=0: k within tile
    int bnp = (tid & 7) * 8;       // BT=0: n offset

    auto loadA = [&](int k0, ushort4& v0, ushort4& v1) {
        int gm = row0 + ar;
        int gk = k0 + ako;
        v0 = zu; v1 = zu;
        if (gm < M) {
            if (gk + 4 <= K) v0 = *(const ushort4*)&Abf[(long)gm * K + gk];
            if (gk + 8 <= K) v1 = *(const ushort4*)&Abf[(long)gm * K + gk + 4];
        }
    };
    auto loadB = [&](int k0, ushort4& v0, ushort4& v1) {
        v0 = zu; v1 = zu;
        if (BT) {
            int gn = col0 + ar;
            int gk = k0 + ako;
            if (gn < Nc) {
                if (gk + 4 <= K) v0 = *(const ushort4*)&Bb[(long)gn * K + gk];
                if (gk + 8 <= K) v1 = *(const ushort4*)&Bb[(long)gn * K + gk + 4];
            }
        } else {
            int gk = k0 + bkk;
            int gn0 = col0 + bnp;
            if (gk < K) {
                if (gn0 + 4 <= Nc) v0 = *(const ushort4*)&Bb[(long)gk * Nc + gn0];
                if (gn0 + 8 <= Nc) v1 = *(const ushort4*)&Bb[(long)gk * Nc + gn0 + 4];
            }
        }
    };

    ushort4 a0, a1, b0, b1;
    ushort4 na0 = zu, na1 = zu, nb0 = zu, nb1 = zu;
    loadA(0, a0, a1);
    loadB(0, b0, b1);

    for (int k0 = 0; k0 < K; k0 += 32) {
        int kn = k0 + 32;
        if (kn < K) {            // prefetch next tile into regs (issues early)
            loadA(kn, na0, na1);
            loadB(kn, nb0, nb1);
        }
        // write current tile to LDS
        *(ushort4*)&As[ar * LDSK + ako]     = a0;
        *(ushort4*)&As[ar * LDSK + ako + 4] = a1;
        if (BT) {
            *(ushort4*)&Bs[ar * LDSK + ako]     = b0;
            *(ushort4*)&Bs[ar * LDSK + ako + 4] = b1;
        } else {
            Bs[(bnp + 0) * LDSK + bkk] = b0.x;
            Bs[(bnp + 1) * LDSK + bkk] = b0.y;
            Bs[(bnp + 2) * LDSK + bkk] = b0.z;
            Bs[(bnp + 3) * LDSK + bkk] = b0.w;
            Bs[(bnp + 4) * LDSK + bkk] = b1.x;
            Bs[(bnp + 5) * LDSK + bkk] = b1.y;
            Bs[(bnp + 6) * LDSK + bkk] = b1.z;
            Bs[(bnp + 7) * LDSK + bkk] = b1.w;
        }
        __syncthreads();

        bf8 fa0 = *(const bf8*)&As[(wr + l16) * LDSK + quad * 8];
        bf8 fa1 = *(const bf8*)&As[(wr + 16 + l16) * LDSK + quad * 8];
        bf8 fb0 = *(const bf8*)&Bs[(wc + l16) * LDSK + quad * 8];
        bf8 fb1 = *(const bf8*)&Bs[(wc + 16 + l16) * LDSK + quad * 8];

        acc00 = __builtin_amdgcn_mfma_f32_16x16x32_bf16(fa0, fb0, acc00, 0, 0, 0);
        acc01 = __builtin_amdgcn_mfma_f32_16x16x32_bf16(fa0, fb1, acc01, 0, 0, 0);
        acc10 = __builtin_amdgcn_mfma_f32_16x16x32_bf16(fa1, fb0, acc10, 0, 0, 0);
        acc11 = __builtin_amdgcn_mfma_f32_16x16x32_bf16(fa1, fb1, acc11, 0, 0, 0);
        __syncthreads();

        a0 = na0; a1 = na1; b0 = nb0; b1 = nb1;
    }

    // --- epilogue: D[row=quad*4+r][col=l16] per 16x16 tile ---
    for (int mi = 0; mi < 2; ++mi) {
        for (int ni = 0; ni < 2; ++ni) {
            for (int r = 0; r < 4; ++r) {
                int gm = row0 + wr + mi * 16 + quad * 4 + r;
                int gn = col0 + wc + ni * 16 + l16;
                if (gm >= M || gn >= Nc) continue;
                float v;
                if (mi == 0 && ni == 0) v = acc00[r];
                else if (mi == 0)       v = acc01[r];
                else if (ni == 0)       v = acc10[r];
                else                    v = acc11[r];
                long idx = (long)gm * Nc + gn;
                if (mode == 2) {
                    v += bias1[gn];
                    if (v < 0.0f) v = 0.0f;
                    Cbf[idx] = f2bf(v);
                } else {
                    Cf[idx] = v + bias1[gn];
                }
            }
        }
    }
}

// ---------------------------------------------------------------------------
// Fused h@Whh^T + LSTM pointwise (with register prefetch).
// grid (8 j-blocks, 8 t-blocks), 256 threads; wave w -> j-sub [j0+w*16,+16)
// for ALL FOUR gates, so each thread holds i,f,g,o in registers.
// ---------------------------------------------------------------------------
__global__ __launch_bounds__(256) void whh_lstm_k(
    const unsigned short* hprev, const unsigned short* Whh_bf,
    const float* pregates, float* c, unsigned short* hnew)
{
    __shared__ unsigned short As[64 * LDSK];    // h rows: 64 x 32
    __shared__ unsigned short Bs[256 * LDSK];   // 4 gates x 64 j-rows x 32 k

    int tid = threadIdx.x;
    int wave = tid >> 6;
    int lane = tid & 63;
    int quad = lane >> 4;
    int l16 = lane & 15;
    int j0 = blockIdx.x * 64;
    int row0 = blockIdx.y * 64;

    int ar = tid >> 2;
    int ako = (tid & 3) * 8;
    int bg = tid >> 6;
    int bjj = tid & 63;
    long browbase = (long)(bg * H_ + j0 + bjj) * H_;

    f4 acc[4][4];   // [gate][m]
    #pragma unroll
    for (int g = 0; g < 4; ++g)
        #pragma unroll
        for (int m = 0; m < 4; ++m)
            acc[g][m] = f4{0.f, 0.f, 0.f, 0.f};

    uint4 pa, pb[4];
    uint4 npa = uint4{0,0,0,0};
    uint4 npb[4] = {uint4{0,0,0,0}, uint4{0,0,0,0}, uint4{0,0,0,0}, uint4{0,0,0,0}};

    pa = *(const uint4*)&hprev[(long)(row0 + ar) * H_ + ako];
    #pragma unroll
    for (int i = 0; i < 4; ++i)
        pb[i] = *(const uint4*)&Whh_bf[browbase + i * 8];

    for (int k0 = 0; k0 < H_; k0 += 32) {
        int kn = k0 + 32;
        if (kn < H_) {
            npa = *(const uint4*)&hprev[(long)(row0 + ar) * H_ + kn + ako];
            #pragma unroll
            for (int i = 0; i < 4; ++i)
                npb[i] = *(const uint4*)&Whh_bf[browbase + kn + i * 8];
        }
        *(uint4*)&As[ar * LDSK + ako] = pa;
        #pragma unroll
        for (int i = 0; i < 4; ++i)
            *(uint4*)&Bs[tid * LDSK + i * 8] = pb[i];
        __syncthreads();

        bf8 a[4], b[4];
        #pragma unroll
        for (int m = 0; m < 4; ++m)
            a[m] = *(const bf8*)&As[(m * 16 + l16) * LDSK + quad * 8];
        #pragma unroll
        for (int g = 0; g < 4; ++g)
            b[g] = *(const bf8*)&Bs[(g * 64 + wave * 16 + l16) * LDSK + quad * 8];

        #pragma unroll
        for (int g = 0; g < 4; ++g)
            #pragma unroll
            for (int m = 0; m < 4; ++m)
                acc[g][m] = __builtin_amdgcn_mfma_f32_16x16x32_bf16(a[m], b[g], acc[g][m], 0, 0, 0);
        __syncthreads();

        pa = npa;
        #pragma unroll
        for (int i = 0; i < 4; ++i) pb[i] = npb[i];
    }

    // epilogue: LSTM pointwise; D row = m*16 + quad*4 + r, col = l16
    int j = j0 + wave * 16 + l16;
    #pragma unroll
    for (int m = 0; m < 4; ++m) {
        #pragma unroll
        for (int r = 0; r < 4; ++r) {
            int t = row0 + m * 16 + quad * 4 + r;
            const float* pg = pregates + (long)t * FOURH;
            float gi = pg[j]        + acc[0][m][r];
            float gf = pg[512 + j]  + acc[1][m][r];
            float gg = pg[1024 + j] + acc[2][m][r];
            float go = pg[1536 + j] + acc[3][m][r];
            float ig = 1.0f / (1.0f + expf(-gi));
            float fg = 1.0f / (1.0f + expf(-gf));
            float g2 = tanhf(gg);
            float og = 1.0f / (1.0f + expf(-go));
            long ci = (long)t * H_ + j;
            float cn = fg * c[ci] + ig * g2;
            c[ci] = cn;
            hnew[ci] = f2bf(og * tanhf(cn));
        }
    }
}

extern "C" void kernel_launch(void* const* d_in, const int* in_sizes, int n_in,
                              void* d_out, int out_size, void* d_ws, size_t ws_size,
                              hipStream_t stream)
{
    const float* feat  = (const float*)d_in[0];
    const float* adjin = (const float*)d_in[1];
    const float* stdv  = (const float*)d_in[2];
    const float* meanv = (const float*)d_in[3];
    const float* gcnW  = (const float*)d_in[4];
    const float* gcnb  = (const float*)d_in[5];
    const float* Wih   = (const float*)d_in[6];
    const float* Whh   = (const float*)d_in[7];
    const float* bih   = (const float*)d_in[8];
    const float* bhh   = (const float*)d_in[9];
    const float* W1    = (const float*)d_in[10];
    const float* b1    = (const float*)d_in[11];
    const float* W2    = (const float*)d_in[12];
    const float* b2    = (const float*)d_in[13];
    const float* W3    = (const float*)d_in[14];
    const float* b3    = (const float*)d_in[15];
    const float* W4    = (const float*)d_in[16];
    const float* b4    = (const float*)d_in[17];
    float* out = (float*)d_out;

    // 5-slot gates layout needs ~31.3 MB (proven ws >= 49.6 MB in prior rounds)
    int five = (ws_size >= (size_t)31400000u) ? 1 : 0;
    int slots = five ? 5 : 1;

    float* gates   = (float*)d_ws;                       // slots * 1,048,576 f
    float* c       = gates + (long)slots * 1048576;      // 262,144 f
    float* biasAll = c + 262144;                         // 2,048 f
    unsigned short* Y       = (unsigned short*)(biasAll + 2048);  // 5*65,536 us
    unsigned short* h1_bf   = Y + 5 * 65536;             // 262,144
    unsigned short* h2_bf   = h1_bf + 262144;            // 262,144
    unsigned short* m1_bf   = h2_bf + 262144;            // 262,144
    unsigned short* m2_bf   = m1_bf + 262144;            // 526,336
    unsigned short* m3_bf   = m2_bf + 526336;            // 262,144
    unsigned short* Whh_bf  = m3_bf + 262144;            // 1,048,576
    unsigned short* W1_bf   = Whh_bf + 1048576;          // 262,144
    unsigned short* W2_bf   = W1_bf + 262144;            // 526,336
    unsigned short* W3_bf   = W2_bf + 526336;            // 526,336
    unsigned short* W4_bf   = W3_bf + 526336;            // 61,440
    unsigned short* Wih2_bf = W4_bf + 61440;             // 262,144

    // weight preprocessing (graph-safe: identical work every call)
    cast_k<<<(1048576 + 255) / 256, 256, 0, stream>>>(Whh, Whh_bf, 1048576);
    cast_k<<<(262144 + 255) / 256, 256, 0, stream>>>(W1, W1_bf, 262144);
    cast_k<<<(526336 + 255) / 256, 256, 0, stream>>>(W2, W2_bf, 526336);
    cast_k<<<(526336 + 255) / 256, 256, 0, stream>>>(W3, W3_bf, 526336);
    cast_k<<<(61440 + 255) / 256, 256, 0, stream>>>(W4, W4_bf, 61440);
    wih2_k<<<FOURH, 256, 0, stream>>>(Wih, gcnW, gcnb, bih, bhh, Wih2_bf, biasAll);

    init_k<<<1024, 256, 0, stream>>>(h1_bf, c, feat, out);

    // all 5 encoder frames' reduced GCN in one launch
    gcn_enc_y<<<5 * T_, 128, 0, stream>>>(feat, adjin, Y);
    if (five)   // batched pre-gates for all encoder steps: [2560,128] @ Wih2^T
        mgemm_t<1><<<dim3(32, 40), 256, 0, stream>>>(Y, Wih2_bf, biasAll,
                                                     gates, (unsigned short*)0,
                                                     5 * T_, FOURH, K2_, 3);

    for (int step = 0; step < 7; ++step) {
        float* gs;
        if (step < 5) {
            if (five) {
                gs = gates + (long)step * 1048576;
            } else {
                gs = gates;
                mgemm_t<1><<<dim3(32, 8), 256, 0, stream>>>(Y + (long)step * 65536,
                                                            Wih2_bf, biasAll,
                                                            gs, (unsigned short*)0,
                                                            T_, FOURH, K2_, 3);
            }
        } else {
            gs = gates;   // slot 0 free after step 0
            gcn_dec_y<<<T_, 128, 0, stream>>>(out + (long)step * PRED_SZ,
                                              stdv, meanv, Y);
            mgemm_t<1><<<dim3(32, 8), 256, 0, stream>>>(Y, Wih2_bf, biasAll,
                                                        gs, (unsigned short*)0,
                                                        T_, FOURH, K2_, 3);
        }

        unsigned short* hp = (step & 1) ? h2_bf : h1_bf;
        unsigned short* hn = (step & 1) ? h1_bf : h2_bf;
        whh_lstm_k<<<dim3(8, 8), 256, 0, stream>>>(hp, Whh_bf, gs, c, hn);

        // MLP: h -> 512 -> 1028 -> 512 -> 120 (pred written into out)
        mgemm_t<0><<<dim3(8, 8), 256, 0, stream>>>(hn, W1_bf, b1,
                                                   (float*)0, m1_bf, T_, 512, 512, 2);
        mgemm_t<0><<<dim3(17, 8), 256, 0, stream>>>(m1_bf, W2_bf, b2,
                                                    (float*)0, m2_bf, T_, 1028, 512, 2);
        mgemm_t<0><<<dim3(8, 8), 256, 0, stream>>>(m2_bf, W3_bf, b3,
                                                   (float*)0, m3_bf, T_, 512, 1028, 2);
        mgemm_t<0><<<dim3(2, 8), 256, 0, stream>>>(m3_bf, W4_bf, b4,
                                                   out + (long)(step + 1) * PRED_SZ,
                                                   (unsigned short*)0, T_, 120, 512, 3);
    }
}

// Round 5
// 650.303 us; speedup vs baseline: 2.6487x; 1.7706x over previous
//
#include <hip/hip_runtime.h>

#define T_ 512
#define N_ 60
#define F_ 2
#define C_ 64
#define H_ 512
#define IN_ 3840
#define FOURH 2048
#define PRED_SZ 61440
#define ADJ_SZ 1843200
#define K2_ 128    // padded reduced-K for the Wih2 GEMM (120 real + 8 zero)
#define LDSK 40    // padded LDS row stride in bf16 units (2-way conflicts only)

typedef __attribute__((ext_vector_type(8))) short bf8;
typedef __attribute__((ext_vector_type(4))) float f4;

__device__ __forceinline__ unsigned short f2bf(float f)
{
    unsigned int u = __float_as_uint(f);
    u = (u + 0x7FFFu + ((u >> 16) & 1u)) >> 16;
    return (unsigned short)u;
}

// cast fp32 -> bf16 (weights, once per launch)
__global__ void cast_k(const float* src, unsigned short* dst, int n)
{
    int i = blockIdx.x * 256 + threadIdx.x;
    if (i < n) dst[i] = f2bf(src[i]);
}

// h (both ping-pong buffers) = 0, c = 0, out frame 0 = feature_input[0]
__global__ void init_k(unsigned short* h_bf, float* c, const float* feat, float* out)
{
    int i = blockIdx.x * 256 + threadIdx.x;   // 1024 blocks -> 262144
    h_bf[i] = 0;
    h_bf[i + 262144] = 0;   // second ping-pong buffer (contiguous)
    c[i] = 0.0f;
    if (i < PRED_SZ) out[i] = feat[i];
}

// ---------------------------------------------------------------------------
// Wih2[o, n*2+f] = sum_c Wih[o, n*64+c] * W[f,c]   (2048 x 120, pad to 128)
// biasAll[o] = bih[o] + bhh[o] + sum_k Wih[o,k]*b[k&63]
// ---------------------------------------------------------------------------
__global__ __launch_bounds__(256) void wih2_k(
    const float* Wih, const float* W, const float* b,
    const float* bih, const float* bhh,
    unsigned short* Wih2_bf, float* biasAll)
{
    __shared__ float row[IN_];     // 3840 floats
    __shared__ float wc[2][64];
    __shared__ float bb[64];
    __shared__ float red[256];

    int o = blockIdx.x;
    int tid = threadIdx.x;

    if (tid < 128) wc[tid >> 6][tid & 63] = W[tid];   // W is [2][64] row-major
    if (tid < 64) bb[tid] = b[tid];
    for (int k = tid; k < IN_; k += 256) row[k] = Wih[(long)o * IN_ + k];
    __syncthreads();

    if (tid < 128) {
        float s = 0.0f;
        if (tid < 120) {
            int n = tid >> 1;
            int f = tid & 1;
            for (int c = 0; c < 64; ++c) s += row[n * 64 + c] * wc[f][c];
        }
        Wih2_bf[(long)o * K2_ + tid] = f2bf(s);   // pad cols 120..127 = 0
    }

    float sb = 0.0f;
    for (int k = tid; k < IN_; k += 256) sb += row[k] * bb[k & 63];
    red[tid] = sb;
    __syncthreads();
    for (int s = 128; s > 0; s >>= 1) {
        if (tid < s) red[tid] += red[tid + s];
        __syncthreads();
    }
    if (tid == 0) biasAll[o] = bih[o] + bhh[o] + red[0];
}

// ---------------------------------------------------------------------------
// Encoder GCN (reduced): Y[t, n*2+f] = norm_n * sum_j A_nj * norm_j * x[j,f]
// blockIdx.x = frame*512 + t ; 128 threads. Output bf16 [row][128], pad = 0.
// ---------------------------------------------------------------------------
__global__ __launch_bounds__(128) void gcn_enc_y(
    const float* x, const float* adj, unsigned short* Y)
{
    __shared__ float sA[N_][N_];
    __shared__ float sx[N_][2];
    __shared__ float snorm[N_];

    int frame = blockIdx.x >> 9;
    int t = blockIdx.x & 511;
    const float* xf = x + (long)frame * PRED_SZ + (long)t * 120;
    const float* af = adj + (long)frame * ADJ_SZ + (long)t * 3600;
    int tid = threadIdx.x;

    for (int l = tid; l < N_ * N_; l += 128) {
        int i = l / N_;
        int j = l - i * N_;
        float a = af[l];
        if (i == j) a += 1.0f;
        sA[i][j] = a;
    }
    if (tid < 120) sx[tid >> 1][tid & 1] = xf[tid];
    __syncthreads();

    if (tid < N_) {
        float d = 0.0f;
        for (int j = 0; j < N_; ++j) d += sA[tid][j];
        snorm[tid] = (d > 0.0f) ? rsqrtf(d) : 0.0f;
    }
    __syncthreads();

    if (tid < 128) {
        float y = 0.0f;
        if (tid < 120) {
            int n = tid >> 1;
            int f = tid & 1;
            float s = 0.0f;
            for (int j = 0; j < N_; ++j) s += sA[n][j] * snorm[j] * sx[j][f];
            y = snorm[n] * s;
        }
        Y[(long)blockIdx.x * K2_ + tid] = f2bf(y);
    }
}

// ---------------------------------------------------------------------------
// Decoder GCN (reduced): radius graph from pred, then Y as above.
// ---------------------------------------------------------------------------
__global__ __launch_bounds__(128) void gcn_dec_y(
    const float* pred, const float* stdv, const float* meanv, unsigned short* Y)
{
    __shared__ float sA[N_][N_];
    __shared__ float sx[N_][2];   // raw pred (GCN features)
    __shared__ float dx0[N_];
    __shared__ float dx1[N_];
    __shared__ int sex[N_];
    __shared__ float snorm[N_];

    int t = blockIdx.x;
    int tid = threadIdx.x;
    const float* pr = pred + (long)t * 120;

    if (tid < 120) sx[tid >> 1][tid & 1] = pr[tid];
    if (tid < N_) {
        float vx = pr[tid * 2 + 0] * stdv[0] + meanv[0];
        float vy = pr[tid * 2 + 1] * stdv[1] + meanv[1];
        dx0[tid] = vx;
        dx1[tid] = vy;
        sex[tid] = (vx > 0.04f) && (vy > 0.04f);
    }
    __syncthreads();

    for (int l = tid; l < N_ * N_; l += 128) {
        int i = l / N_;
        int j = l - i * N_;
        float ddx = dx0[i] - dx0[j];
        float ddy = dx1[i] - dx1[j];
        float d = sqrtf(ddx * ddx + ddy * ddy);
        int conn = ((d > 0.0f) && (d < 10.0f)) || (i == j);
        float a = (sex[i] && sex[j] && conn) ? 1.0f : 0.0f;
        if (i == j) a += 1.0f;     // GCN self-loop on top of radius graph
        sA[i][j] = a;
    }
    __syncthreads();

    if (tid < N_) {
        float d = 0.0f;
        for (int j = 0; j < N_; ++j) d += sA[tid][j];
        snorm[tid] = (d > 0.0f) ? rsqrtf(d) : 0.0f;
    }
    __syncthreads();

    if (tid < 128) {
        float y = 0.0f;
        if (tid < 120) {
            int n = tid >> 1;
            int f = tid & 1;
            float s = 0.0f;
            for (int j = 0; j < N_; ++j) s += sA[n][j] * snorm[j] * sx[j][f];
            y = snorm[n] * s;
        }
        Y[(long)t * K2_ + tid] = f2bf(y);
    }
}

// ---------------------------------------------------------------------------
// 32x32-tile MFMA GEMM: 4 waves, each wave one 16x16 quadrant (1 MFMA/k-step).
// 4x the block count of the 64x64 version -> occupancy for small M,N shapes.
// BT=1: B stored [Nc][K]; BT=0: B stored [K][Nc].
// mode 2: Cbf = bf16(relu(acc + bias1)); mode 3: Cf = acc + bias1.
// Register prefetch double-buffering.
// ---------------------------------------------------------------------------
template<int BT>
__global__ __launch_bounds__(256) void gemm32(
    const unsigned short* Abf, const unsigned short* Bb,
    const float* bias1, float* Cf, unsigned short* Cbf,
    int M, int Nc, int K, int mode)
{
    __shared__ unsigned short As[32 * LDSK];
    __shared__ unsigned short Bs[32 * LDSK];

    int tid = threadIdx.x;
    int wave = tid >> 6;
    int wt = wave >> 1, wj = wave & 1;
    int lane = tid & 63;
    int quad = lane >> 4;
    int l16 = lane & 15;
    int row0 = blockIdx.y * 32;
    int col0 = blockIdx.x * 32;

    f4 acc = {0.f, 0.f, 0.f, 0.f};
    const ushort4 zu = make_ushort4(0, 0, 0, 0);

    int sr = tid >> 3;          // 0..31
    int sko = (tid & 7) * 4;    // 0..28

    auto loadA = [&](int k0, ushort4& v) {
        int gm = row0 + sr, gk = k0 + sko;
        v = zu;
        if (gm < M && gk + 4 <= K) v = *(const ushort4*)&Abf[(long)gm * K + gk];
    };
    auto loadB1 = [&](int k0, ushort4& v) {
        int gn = col0 + sr, gk = k0 + sko;
        v = zu;
        if (gn < Nc && gk + 4 <= K) v = *(const ushort4*)&Bb[(long)gn * K + gk];
    };
    auto loadB0 = [&](int k0, ushort4& v) {
        int gk = k0 + sr;            // k index 0..31
        int gn0 = col0 + sko;        // n offset 0..28
        v = zu;
        if (gk < K) {
            if (gn0 + 4 <= Nc) {
                v = *(const ushort4*)&Bb[(long)gk * Nc + gn0];
            } else {
                unsigned short tmp[4] = {0, 0, 0, 0};
                for (int i = 0; i < 4; ++i)
                    if (gn0 + i < Nc) tmp[i] = Bb[(long)gk * Nc + gn0 + i];
                v = make_ushort4(tmp[0], tmp[1], tmp[2], tmp[3]);
            }
        }
    };

    ushort4 a0, b0, na0 = zu, nb0 = zu;
    loadA(0, a0);
    if (BT) loadB1(0, b0); else loadB0(0, b0);

    int niter = (K + 31) / 32;
    for (int it = 0; it < niter; ++it) {
        if (it + 1 < niter) {
            int kn = (it + 1) * 32;
            loadA(kn, na0);
            if (BT) loadB1(kn, nb0); else loadB0(kn, nb0);
        }
        *(ushort4*)&As[sr * LDSK + sko] = a0;
        if (BT) {
            *(ushort4*)&Bs[sr * LDSK + sko] = b0;
        } else {
            Bs[(sko + 0) * LDSK + sr] = b0.x;
            Bs[(sko + 1) * LDSK + sr] = b0.y;
            Bs[(sko + 2) * LDSK + sr] = b0.z;
            Bs[(sko + 3) * LDSK + sr] = b0.w;
        }
        __syncthreads();

        bf8 fa = *(const bf8*)&As[(wt * 16 + l16) * LDSK + quad * 8];
        bf8 fb = *(const bf8*)&Bs[(wj * 16 + l16) * LDSK + quad * 8];
        acc = __builtin_amdgcn_mfma_f32_16x16x32_bf16(fa, fb, acc, 0, 0, 0);
        __syncthreads();

        a0 = na0; b0 = nb0;
    }

    // epilogue: D row = wt*16 + quad*4 + r, col = wj*16 + l16
    int gn = col0 + wj * 16 + l16;
    if (gn < Nc) {
        float bsv = bias1[gn];
        #pragma unroll
        for (int r = 0; r < 4; ++r) {
            int gm = row0 + wt * 16 + quad * 4 + r;
            if (gm >= M) continue;
            float v = acc[r] + bsv;
            long idx = (long)gm * Nc + gn;
            if (mode == 2) {
                if (v < 0.0f) v = 0.0f;
                Cbf[idx] = f2bf(v);
            } else {
                Cf[idx] = v;
            }
        }
    }
}

// ---------------------------------------------------------------------------
// Fused h@Whh^T + LSTM pointwise, high-occupancy version.
// grid (16 j-blocks, 16 t-blocks) = 256 blocks; block tile 32t x 32j x 4 gates.
// Wave (wt,wj) computes ALL FOUR gates for its 16x16 (t,j) cell, so each
// thread holds i,f,g,o in registers -> LSTM epilogue thread-local.
// ---------------------------------------------------------------------------
__global__ __launch_bounds__(256) void whh_lstm_k(
    const unsigned short* hprev, const unsigned short* Whh_bf,
    const float* pregates, float* c, unsigned short* hnew)
{
    __shared__ unsigned short As[32 * LDSK];     // h rows: 32 x 32
    __shared__ unsigned short Bs[128 * LDSK];    // 4 gates x 32 j-rows x 32 k

    int tid = threadIdx.x;
    int wave = tid >> 6;
    int wt = wave >> 1, wj = wave & 1;
    int lane = tid & 63;
    int quad = lane >> 4;
    int l16 = lane & 15;
    int j0 = blockIdx.x * 32;
    int row0 = blockIdx.y * 32;

    // A staging: 256 thr x 4 bf16 (one ushort4)
    int sr = tid >> 3;          // 0..31
    int sko = (tid & 7) * 4;    // 0..28
    // B staging: 128 rows x 32 k ; 256 thr x 16 bf16 (two uint4)
    int br = tid >> 1;          // 0..127  (gate = br>>5, jj = br&31)
    int bko = (tid & 1) * 16;   // 0 or 16
    long browbase = (long)((br >> 5) * H_ + j0 + (br & 31)) * H_;

    f4 acc[4];
    #pragma unroll
    for (int g = 0; g < 4; ++g) acc[g] = f4{0.f, 0.f, 0.f, 0.f};

    ushort4 pa, npa = make_ushort4(0, 0, 0, 0);
    uint4 pb0, pb1, npb0 = uint4{0,0,0,0}, npb1 = uint4{0,0,0,0};

    pa  = *(const ushort4*)&hprev[(long)(row0 + sr) * H_ + sko];
    pb0 = *(const uint4*)&Whh_bf[browbase + bko];
    pb1 = *(const uint4*)&Whh_bf[browbase + bko + 8];

    for (int k0 = 0; k0 < H_; k0 += 32) {
        int kn = k0 + 32;
        if (kn < H_) {
            npa  = *(const ushort4*)&hprev[(long)(row0 + sr) * H_ + kn + sko];
            npb0 = *(const uint4*)&Whh_bf[browbase + kn + bko];
            npb1 = *(const uint4*)&Whh_bf[browbase + kn + bko + 8];
        }
        *(ushort4*)&As[sr * LDSK + sko] = pa;
        *(uint4*)&Bs[br * LDSK + bko]     = pb0;
        *(uint4*)&Bs[br * LDSK + bko + 8] = pb1;
        __syncthreads();

        bf8 fa = *(const bf8*)&As[(wt * 16 + l16) * LDSK + quad * 8];
        #pragma unroll
        for (int g = 0; g < 4; ++g) {
            bf8 fb = *(const bf8*)&Bs[(g * 32 + wj * 16 + l16) * LDSK + quad * 8];
            acc[g] = __builtin_amdgcn_mfma_f32_16x16x32_bf16(fa, fb, acc[g], 0, 0, 0);
        }
        __syncthreads();

        pa = npa; pb0 = npb0; pb1 = npb1;
    }

    // epilogue: LSTM pointwise; t = row0 + wt*16 + quad*4 + r, j = j0 + wj*16 + l16
    int j = j0 + wj * 16 + l16;
    #pragma unroll
    for (int r = 0; r < 4; ++r) {
        int t = row0 + wt * 16 + quad * 4 + r;
        const float* pg = pregates + (long)t * FOURH;
        float gi = pg[j]        + acc[0][r];
        float gf = pg[512 + j]  + acc[1][r];
        float gg = pg[1024 + j] + acc[2][r];
        float go = pg[1536 + j] + acc[3][r];
        float ig = 1.0f / (1.0f + expf(-gi));
        float fg = 1.0f / (1.0f + expf(-gf));
        float g2 = tanhf(gg);
        float og = 1.0f / (1.0f + expf(-go));
        long ci = (long)t * H_ + j;
        float cn = fg * c[ci] + ig * g2;
        c[ci] = cn;
        hnew[ci] = f2bf(og * tanhf(cn));
    }
}

extern "C" void kernel_launch(void* const* d_in, const int* in_sizes, int n_in,
                              void* d_out, int out_size, void* d_ws, size_t ws_size,
                              hipStream_t stream)
{
    const float* feat  = (const float*)d_in[0];
    const float* adjin = (const float*)d_in[1];
    const float* stdv  = (const float*)d_in[2];
    const float* meanv = (const float*)d_in[3];
    const float* gcnW  = (const float*)d_in[4];
    const float* gcnb  = (const float*)d_in[5];
    const float* Wih   = (const float*)d_in[6];
    const float* Whh   = (const float*)d_in[7];
    const float* bih   = (const float*)d_in[8];
    const float* bhh   = (const float*)d_in[9];
    const float* W1    = (const float*)d_in[10];
    const float* b1    = (const float*)d_in[11];
    const float* W2    = (const float*)d_in[12];
    const float* b2    = (const float*)d_in[13];
    const float* W3    = (const float*)d_in[14];
    const float* b3    = (const float*)d_in[15];
    const float* W4    = (const float*)d_in[16];
    const float* b4    = (const float*)d_in[17];
    float* out = (float*)d_out;

    // 5-slot gates layout needs ~31.3 MB (ws >= 49 MB proven in prior rounds)
    int five = (ws_size >= (size_t)31400000u) ? 1 : 0;
    int slots = five ? 5 : 1;

    float* gates   = (float*)d_ws;                       // slots * 1,048,576 f
    float* c       = gates + (long)slots * 1048576;      // 262,144 f
    float* biasAll = c + 262144;                         // 2,048 f
    unsigned short* Y       = (unsigned short*)(biasAll + 2048);  // 5*65,536 us
    unsigned short* h1_bf   = Y + 5 * 65536;             // 262,144
    unsigned short* h2_bf   = h1_bf + 262144;            // 262,144
    unsigned short* m1_bf   = h2_bf + 262144;            // 262,144
    unsigned short* m2_bf   = m1_bf + 262144;            // 526,336
    unsigned short* m3_bf   = m2_bf + 526336;            // 262,144
    unsigned short* Whh_bf  = m3_bf + 262144;            // 1,048,576
    unsigned short* W1_bf   = Whh_bf + 1048576;          // 262,144
    unsigned short* W2_bf   = W1_bf + 262144;            // 526,336
    unsigned short* W3_bf   = W2_bf + 526336;            // 526,336
    unsigned short* W4_bf   = W3_bf + 526336;            // 61,440
    unsigned short* Wih2_bf = W4_bf + 61440;             // 262,144

    // weight preprocessing (graph-safe: identical work every call)
    cast_k<<<(1048576 + 255) / 256, 256, 0, stream>>>(Whh, Whh_bf, 1048576);
    cast_k<<<(262144 + 255) / 256, 256, 0, stream>>>(W1, W1_bf, 262144);
    cast_k<<<(526336 + 255) / 256, 256, 0, stream>>>(W2, W2_bf, 526336);
    cast_k<<<(526336 + 255) / 256, 256, 0, stream>>>(W3, W3_bf, 526336);
    cast_k<<<(61440 + 255) / 256, 256, 0, stream>>>(W4, W4_bf, 61440);
    wih2_k<<<FOURH, 256, 0, stream>>>(Wih, gcnW, gcnb, bih, bhh, Wih2_bf, biasAll);

    init_k<<<1024, 256, 0, stream>>>(h1_bf, c, feat, out);

    // all 5 encoder frames' reduced GCN in one launch
    gcn_enc_y<<<5 * T_, 128, 0, stream>>>(feat, adjin, Y);
    if (five)   // batched pre-gates for all encoder steps: [2560,128] @ Wih2^T
        gemm32<1><<<dim3(64, 80), 256, 0, stream>>>(Y, Wih2_bf, biasAll,
                                                    gates, (unsigned short*)0,
                                                    5 * T_, FOURH, K2_, 3);

    for (int step = 0; step < 7; ++step) {
        float* gs;
        if (step < 5) {
            if (five) {
                gs = gates + (long)step * 1048576;
            } else {
                gs = gates;
                gemm32<1><<<dim3(64, 16), 256, 0, stream>>>(Y + (long)step * 65536,
                                                            Wih2_bf, biasAll,
                                                            gs, (unsigned short*)0,
                                                            T_, FOURH, K2_, 3);
            }
        } else {
            gs = gates;   // slot 0 free after step 0
            gcn_dec_y<<<T_, 128, 0, stream>>>(out + (long)step * PRED_SZ,
                                              stdv, meanv, Y);
            gemm32<1><<<dim3(64, 16), 256, 0, stream>>>(Y, Wih2_bf, biasAll,
                                                        gs, (unsigned short*)0,
                                                        T_, FOURH, K2_, 3);
        }

        unsigned short* hp = (step & 1) ? h2_bf : h1_bf;
        unsigned short* hn = (step & 1) ? h1_bf : h2_bf;
        whh_lstm_k<<<dim3(16, 16), 256, 0, stream>>>(hp, Whh_bf, gs, c, hn);

        // MLP: h -> 512 -> 1028 -> 512 -> 120 (pred written into out)
        gemm32<0><<<dim3(16, 16), 256, 0, stream>>>(hn, W1_bf, b1,
                                                    (float*)0, m1_bf, T_, 512, 512, 2);
        gemm32<0><<<dim3(33, 16), 256, 0, stream>>>(m1_bf, W2_bf, b2,
                                                    (float*)0, m2_bf, T_, 1028, 512, 2);
        gemm32<0><<<dim3(16, 16), 256, 0, stream>>>(m2_bf, W3_bf, b3,
                                                    (float*)0, m3_bf, T_, 512, 1028, 2);
        gemm32<0><<<dim3(4, 16), 256, 0, stream>>>(m3_bf, W4_bf, b4,
                                                   out + (long)(step + 1) * PRED_SZ,
                                                   (unsigned short*)0, T_, 120, 512, 3);
    }
}